// Round 1
// baseline (406.610 us; speedup 1.0000x reference)
//
#include <hip/hip_runtime.h>

#define HDIM 64
#define BLK  256

// tanh(x) = 1 - 2/(exp(2x)+1); exp(2x) = 2^(x * 2*log2(e)).
// v_exp_f32 / v_rcp_f32 are ~1 ulp -> abs error ~1e-7, saturates correctly at +-inf.
__device__ __forceinline__ float tanh_fast(float v) {
    float e = __builtin_amdgcn_exp2f(v * 2.8853900817779268f);
    float r = __builtin_amdgcn_rcpf(e + 1.0f);
    return fmaf(-2.0f, r, 1.0f);
}

// ---------------------------------------------------------------------------
// Table build (runs once per launch, ~3 us):
//   ct[h*64+k] = {W2[h,k], W2[h,k]*W1[k,0], W2[h,k]*W1[k,1], W2[h,k]*W1[k,2]}
//   ht[h]      = {b2[h],  W3[0,h], W3[1,h], W3[2,h]}
// Same folded products as the previous LDS kernel -> identical numerics.
// ---------------------------------------------------------------------------
__global__ void build_tables(const float* __restrict__ W1,
                             const float* __restrict__ W2,
                             const float* __restrict__ b2,
                             const float* __restrict__ W3,
                             float4* __restrict__ ct,
                             float4* __restrict__ ht)
{
    const int idx = blockIdx.x * 256 + threadIdx.x;
    if (idx < HDIM * HDIM) {
        const int k = idx & (HDIM - 1);
        const float w2 = W2[idx];
        ct[idx] = make_float4(w2, w2 * W1[k * 3 + 0],
                                  w2 * W1[k * 3 + 1],
                                  w2 * W1[k * 3 + 2]);
    }
    if (idx < HDIM) {
        ht[idx] = make_float4(b2[idx], W3[idx], W3[HDIM + idx], W3[2 * HDIM + idx]);
    }
}

// ---------------------------------------------------------------------------
// Main kernel, SMEM-constant version. The CT row reads are wave-uniform
// (index depends only on h,k), from a const __restrict__ global pointer the
// kernel never writes -> compiler selects s_load_dwordx4 (merged to x8/x16).
// Inner iteration is then 4 v_fma_f32 with one SGPR operand each: no LDS,
// no extra VALU. LDS pipe (the old 7.16 cyc/iter bottleneck) goes idle;
// occupancy cap moves from LDS (8 waves/CU) to VGPR (~12 waves/CU).
// ---------------------------------------------------------------------------
__global__ __launch_bounds__(BLK) void curl_smem(
    const float* __restrict__ x,  const float* __restrict__ W1,
    const float* __restrict__ b1,
    const float4* __restrict__ ct, const float4* __restrict__ ht,
    float* __restrict__ out, int npts)
{
    const int n = blockIdx.x * BLK + threadIdx.x;
    if (n >= npts) return;

    const float x0 = x[n * 3 + 0];
    const float x1 = x[n * 3 + 1];
    const float x2 = x[n * 3 + 2];

    // Layer 1: h1 = tanh(W1 x + b1); D1 = 1 - h1^2. W1/b1 reads are uniform
    // (s_load, K$-resident). Arrays stay in VGPRs (static indices).
    float h1a[HDIM], d1a[HDIM];
#pragma unroll
    for (int i = 0; i < HDIM; ++i) {
        float a = fmaf(W1[i * 3 + 0], x0, b1[i]);
        a = fmaf(W1[i * 3 + 1], x1, a);
        a = fmaf(W1[i * 3 + 2], x2, a);
        const float th = tanh_fast(a);
        h1a[i] = th;
        d1a[i] = fmaf(-th, th, 1.0f);
    }

    // Layer 2 + Jacobian + curl, fused over h.
    // s0  = b2[h] + sum_k W2[h,k] * h1[k]
    // u_d = sum_k  D1[k] * (W2[h,k]*W1[k,d])
    // curl += eps contraction of W3[:,h] * D2[h] * u
    float c0 = 0.f, c1 = 0.f, c2 = 0.f;
#pragma unroll 1
    for (int h = 0; h < HDIM; ++h) {
        const float4 hh = ht[h];               // uniform -> SGPRs
        float s0 = hh.x, u0 = 0.f, u1 = 0.f, u2 = 0.f;
        const float4* __restrict__ row = ct + h * HDIM;
#pragma unroll
        for (int k = 0; k < HDIM; ++k) {
            const float4 cw = row[k];          // uniform -> s_load_dwordx4
            s0 = fmaf(cw.x, h1a[k], s0);
            u0 = fmaf(cw.y, d1a[k], u0);
            u1 = fmaf(cw.z, d1a[k], u1);
            u2 = fmaf(cw.w, d1a[k], u2);
        }

        const float th = tanh_fast(s0);
        const float d2 = fmaf(-th, th, 1.0f);
        const float e0 = hh.y * d2;
        const float e1 = hh.z * d2;
        const float e2 = hh.w * d2;
        // curl0 += J21 - J12 ; curl1 += J02 - J20 ; curl2 += J10 - J01
        c0 = fmaf(e2, u1, c0); c0 = fmaf(-e1, u2, c0);
        c1 = fmaf(e0, u2, c1); c1 = fmaf(-e2, u0, c1);
        c2 = fmaf(e1, u0, c2); c2 = fmaf(-e0, u1, c2);
    }

    out[n * 3 + 0] = c0;
    out[n * 3 + 1] = c1;
    out[n * 3 + 2] = c2;
}

// ---------------------------------------------------------------------------
// Fallback (previous best, 391 us): LDS-broadcast CT. Used only if the
// harness workspace is too small for the tables.
// ---------------------------------------------------------------------------
__global__ __launch_bounds__(BLK) void curl_kernel(
    const float* __restrict__ x,  const float* __restrict__ W1,
    const float* __restrict__ b1, const float* __restrict__ W2,
    const float* __restrict__ b2, const float* __restrict__ W3,
    float* __restrict__ out, int npts)
{
    __shared__ float4 sCT[HDIM * HDIM];

    const int t = threadIdx.x;
    for (int idx = t; idx < HDIM * HDIM; idx += BLK) {
        const int k = idx & (HDIM - 1);
        const float w2 = W2[idx];
        sCT[idx] = make_float4(w2, w2 * W1[k * 3 + 0],
                                   w2 * W1[k * 3 + 1],
                                   w2 * W1[k * 3 + 2]);
    }
    __syncthreads();

    const int n = blockIdx.x * BLK + t;
    if (n >= npts) return;

    const float x0 = x[n * 3 + 0];
    const float x1 = x[n * 3 + 1];
    const float x2 = x[n * 3 + 2];

    float h1a[HDIM], d1a[HDIM];
#pragma unroll
    for (int i = 0; i < HDIM; ++i) {
        float a = fmaf(W1[i * 3 + 0], x0, b1[i]);
        a = fmaf(W1[i * 3 + 1], x1, a);
        a = fmaf(W1[i * 3 + 2], x2, a);
        const float th = tanh_fast(a);
        h1a[i] = th;
        d1a[i] = fmaf(-th, th, 1.0f);
    }

    float c0 = 0.f, c1 = 0.f, c2 = 0.f;
    float hb  = b2[0];
    float w30 = W3[0 * HDIM + 0];
    float w31 = W3[1 * HDIM + 0];
    float w32 = W3[2 * HDIM + 0];
#pragma unroll 1
    for (int h = 0; h < HDIM; ++h) {
        float hb_n = 0.f, w30_n = 0.f, w31_n = 0.f, w32_n = 0.f;
        if (h + 1 < HDIM) {
            hb_n  = b2[h + 1];
            w30_n = W3[0 * HDIM + h + 1];
            w31_n = W3[1 * HDIM + h + 1];
            w32_n = W3[2 * HDIM + h + 1];
        }

        float s0 = hb, u0 = 0.f, u1 = 0.f, u2 = 0.f;
        const float4* __restrict__ row = &sCT[h * HDIM];
#pragma unroll
        for (int k = 0; k < HDIM; ++k) {
            const float4 cw = row[k];
            s0 = fmaf(cw.x, h1a[k], s0);
            u0 = fmaf(cw.y, d1a[k], u0);
            u1 = fmaf(cw.z, d1a[k], u1);
            u2 = fmaf(cw.w, d1a[k], u2);
        }

        const float th = tanh_fast(s0);
        const float d2 = fmaf(-th, th, 1.0f);
        const float e0 = w30 * d2;
        const float e1 = w31 * d2;
        const float e2 = w32 * d2;
        c0 = fmaf(e2, u1, c0); c0 = fmaf(-e1, u2, c0);
        c1 = fmaf(e0, u2, c1); c1 = fmaf(-e2, u0, c1);
        c2 = fmaf(e1, u0, c2); c2 = fmaf(-e0, u1, c2);

        hb = hb_n; w30 = w30_n; w31 = w31_n; w32 = w32_n;
    }

    out[n * 3 + 0] = c0;
    out[n * 3 + 1] = c1;
    out[n * 3 + 2] = c2;
}

extern "C" void kernel_launch(void* const* d_in, const int* in_sizes, int n_in,
                              void* d_out, int out_size, void* d_ws, size_t ws_size,
                              hipStream_t stream) {
    const float* x  = (const float*)d_in[0];
    const float* W1 = (const float*)d_in[1];
    const float* b1 = (const float*)d_in[2];
    const float* W2 = (const float*)d_in[3];
    const float* b2 = (const float*)d_in[4];
    const float* W3 = (const float*)d_in[5];
    // d_in[6] (b3) is unused: it cancels in the Jacobian.
    float* out = (float*)d_out;

    const int npts = in_sizes[0] / 3;
    const int grid = (npts + BLK - 1) / BLK;

    const size_t ws_needed = (size_t)(HDIM * HDIM + HDIM) * sizeof(float4); // 66560 B
    if (d_ws != nullptr && ws_size >= ws_needed) {
        float4* ct = (float4*)d_ws;
        float4* ht = ct + HDIM * HDIM;
        hipLaunchKernelGGL(build_tables, dim3((HDIM * HDIM + 255) / 256), dim3(256),
                           0, stream, W1, W2, b2, W3, ct, ht);
        hipLaunchKernelGGL(curl_smem, dim3(grid), dim3(BLK), 0, stream,
                           x, W1, b1, ct, ht, out, npts);
    } else {
        hipLaunchKernelGGL(curl_kernel, dim3(grid), dim3(BLK), 0, stream,
                           x, W1, b1, W2, b2, W3, out, npts);
    }
}

// Round 2
// 315.170 us; speedup vs baseline: 1.2901x; 1.2901x over previous
//
#include <hip/hip_runtime.h>

#define HDIM 64
#define BLK  256
#define KH   32            // k's per thread: 2 threads (a lane pair) share one point
#define ROWS 72            // padded LDS row stride in floats: the two half-rows land
                           // on disjoint 4-bank groups (+36 floats = +4 banks mod 32)

// tanh(x) = 1 - 2/(exp(2x)+1); exp(2x) = 2^(x * 2*log2(e)).
// v_exp_f32 / v_rcp_f32 are ~1 ulp -> abs error ~1e-7, saturates correctly at +-inf.
__device__ __forceinline__ float tanh_fast(float v) {
    float e = __builtin_amdgcn_exp2f(v * 2.8853900817779268f);
    float r = __builtin_amdgcn_rcpf(e + 1.0f);
    return fmaf(-2.0f, r, 1.0f);
}

// Sum across a lane pair (lane 2i <-> 2i+1) on the VALU pipe:
// v_mov_b32 dpp quad_perm:[1,0,3,2] + v_add_f32. No LDS traffic.
__device__ __forceinline__ float pair_sum(float v) {
    int o = __builtin_amdgcn_update_dpp(0, __float_as_int(v), 0xB1, 0xF, 0xF, true);
    return v + __int_as_float(o);
}

// Key restructure vs previous rounds: u_d = sum_k W2[h,k] * (D1[k]*W1[k,d]).
// Folding D1 into g_d[k] = D1[k]*W1[k,d] (once per point) makes all FOUR
// accumulators (s0,u0,u1,u2) share the SAME table scalar W2[h,k]:
// one ds_read_b128 now feeds 16 FMAs (was 4) -> LDS pipe demand /4,
// table shrinks 64KB -> 16KB, and no scalar-chunking (round-1 stall) at all.
// The 256-float per-point register state is split across a lane pair (32 k
// each), recombined with one DPP add per accumulator per h.
__global__ __launch_bounds__(BLK) void curl_pair(
    const float* __restrict__ x,  const float* __restrict__ W1,
    const float* __restrict__ b1, const float* __restrict__ W2,
    const float* __restrict__ b2, const float* __restrict__ W3,
    float* __restrict__ out, int npts)
{
    __shared__ float sW2[HDIM * ROWS];   // 18432 B

    // Stage W2 with the halves of each row separated by 36 floats so the two
    // broadcast addresses per wave hit disjoint bank groups.
    for (int i = threadIdx.x; i < HDIM * HDIM; i += BLK) {
        const int h = i >> 6, k = i & 63;
        sW2[h * ROWS + k + ((k >= KH) ? 4 : 0)] = W2[i];
    }
    __syncthreads();

    const int t = threadIdx.x;
    const int p = blockIdx.x * (BLK / 2) + (t >> 1);
    if (p >= npts) return;
    const int half  = t & 1;
    const int kbase = half * KH;          // this thread's k range
    const int cbase = half * (KH + 4);    // its column base in the padded row

    const float x0 = x[p * 3 + 0];
    const float x1 = x[p * 3 + 1];
    const float x2 = x[p * 3 + 2];

    // Layer 1 for this thread's 32 k's: h1, and g_d = (1-h1^2)*W1[:,d].
    float h1a[KH], g0[KH], g1[KH], g2[KH];   // 128 VGPRs (static indices)
#pragma unroll
    for (int j = 0; j < KH; ++j) {
        const int k = kbase + j;
        const float w10 = W1[k * 3 + 0];
        const float w11 = W1[k * 3 + 1];
        const float w12 = W1[k * 3 + 2];
        float a = fmaf(w10, x0, b1[k]);
        a = fmaf(w11, x1, a);
        a = fmaf(w12, x2, a);
        const float th = tanh_fast(a);
        const float d1 = fmaf(-th, th, 1.0f);
        h1a[j] = th;
        g0[j] = d1 * w10;
        g1[j] = d1 * w11;
        g2[j] = d1 * w12;
    }

    float c0 = 0.f, c1 = 0.f, c2 = 0.f;
#pragma unroll 2
    for (int h = 0; h < HDIM; ++h) {
        const float4* __restrict__ row = (const float4*)&sW2[h * ROWS + cbase];
        float s0 = 0.f, u0 = 0.f, u1 = 0.f, u2 = 0.f;
#pragma unroll
        for (int q = 0; q < KH / 4; ++q) {
            const float4 w = row[q];           // 1 b128 -> 16 FMAs
            const int j = q * 4;
            s0 = fmaf(w.x, h1a[j],   s0); u0 = fmaf(w.x, g0[j],   u0);
            u1 = fmaf(w.x, g1[j],   u1);  u2 = fmaf(w.x, g2[j],   u2);
            s0 = fmaf(w.y, h1a[j+1], s0); u0 = fmaf(w.y, g0[j+1], u0);
            u1 = fmaf(w.y, g1[j+1], u1);  u2 = fmaf(w.y, g2[j+1], u2);
            s0 = fmaf(w.z, h1a[j+2], s0); u0 = fmaf(w.z, g0[j+2], u0);
            u1 = fmaf(w.z, g1[j+2], u1);  u2 = fmaf(w.z, g2[j+2], u2);
            s0 = fmaf(w.w, h1a[j+3], s0); u0 = fmaf(w.w, g0[j+3], u0);
            u1 = fmaf(w.w, g1[j+3], u1);  u2 = fmaf(w.w, g2[j+3], u2);
        }
        // Combine the lane pair's partial sums (both lanes end with the total).
        s0 = pair_sum(s0) + b2[h];
        u0 = pair_sum(u0);
        u1 = pair_sum(u1);
        u2 = pair_sum(u2);

        const float th = tanh_fast(s0);
        const float d2 = fmaf(-th, th, 1.0f);
        const float e0 = W3[0 * HDIM + h] * d2;   // uniform -> s_load, K$-resident
        const float e1 = W3[1 * HDIM + h] * d2;
        const float e2 = W3[2 * HDIM + h] * d2;
        // curl0 += J21 - J12 ; curl1 += J02 - J20 ; curl2 += J10 - J01
        c0 = fmaf(e2, u1, c0); c0 = fmaf(-e1, u2, c0);
        c1 = fmaf(e0, u2, c1); c1 = fmaf(-e2, u0, c1);
        c2 = fmaf(e1, u0, c2); c2 = fmaf(-e0, u1, c2);
    }

    if (half == 0) {
        out[p * 3 + 0] = c0;
        out[p * 3 + 1] = c1;
        out[p * 3 + 2] = c2;
    }
}

extern "C" void kernel_launch(void* const* d_in, const int* in_sizes, int n_in,
                              void* d_out, int out_size, void* d_ws, size_t ws_size,
                              hipStream_t stream) {
    const float* x  = (const float*)d_in[0];
    const float* W1 = (const float*)d_in[1];
    const float* b1 = (const float*)d_in[2];
    const float* W2 = (const float*)d_in[3];
    const float* b2 = (const float*)d_in[4];
    const float* W3 = (const float*)d_in[5];
    // d_in[6] (b3) is unused: it cancels in the Jacobian.
    float* out = (float*)d_out;

    const int npts = in_sizes[0] / 3;
    // 2 threads per point -> each block of 256 threads covers 128 points.
    const int grid = (npts + (BLK / 2) - 1) / (BLK / 2);
    hipLaunchKernelGGL(curl_pair, dim3(grid), dim3(BLK), 0, stream,
                       x, W1, b1, W2, b2, W3, out, npts);
}

// Round 3
// 153.404 us; speedup vs baseline: 2.6506x; 2.0545x over previous
//
#include <hip/hip_runtime.h>

typedef __attribute__((ext_vector_type(8))) short bf16x8;   // 8 bf16 in 4 VGPRs
typedef __attribute__((ext_vector_type(4))) float f32x4;

#define BLK   256
#define NWAVE 4
#define NPT   16      // points per wave-tile; cols per type-tile
#define KPAD  72      // ushort pitch per X^T column (144 B, 16B-aligned)
#define MAXB  1024

union U4 { uint4 u; bf16x8 v; };

// tanh(x) = 1 - 2/(exp(2x)+1); ~1 ulp, saturates correctly.
__device__ __forceinline__ float tanh_fast(float v) {
    float e = __builtin_amdgcn_exp2f(v * 2.8853900817779268f);
    float r = __builtin_amdgcn_rcpf(e + 1.0f);
    return fmaf(-2.0f, r, 1.0f);
}

__device__ __forceinline__ unsigned int packlohi(unsigned int a, unsigned int b) {
    // a,b are fp32 bit patterns; result = {bf16(a) in low16, bf16(b) in high16} (truncation)
    return (a >> 16) | (b & 0xffff0000u);
}

// Split 8 fp32 into bf16 hi/lo planes (hi = truncate, lo = exact residual truncated:
// combined ~16 mantissa bits) and store as one ds_write_b128 per plane.
__device__ __forceinline__ void store8(ushort* dhi, ushort* dlo, const float* v) {
    unsigned int hb[8], lb[8];
#pragma unroll
    for (int j = 0; j < 8; ++j) {
        const unsigned int bits = __float_as_uint(v[j]);
        const unsigned int h = bits & 0xffff0000u;
        hb[j] = h;
        lb[j] = __float_as_uint(v[j] - __uint_as_float(h));
    }
    *(uint4*)dhi = make_uint4(packlohi(hb[0],hb[1]), packlohi(hb[2],hb[3]),
                              packlohi(hb[4],hb[5]), packlohi(hb[6],hb[7]));
    *(uint4*)dlo = make_uint4(packlohi(lb[0],lb[1]), packlohi(lb[2],lb[3]),
                              packlohi(lb[4],lb[5]), packlohi(lb[6],lb[7]));
}

#define MFMA __builtin_amdgcn_mfma_f32_16x16x32_bf16

// GEMM-ified curl: per wave-tile of 16 points, C[64h][64cols] = W2 x [h1|g0|g1|g2]
// via 96 mfma_f32_16x16x32_bf16 (hi/lo bf16 split, 3 terms). Epilogue is lane-local:
// D col = lane&15 = point, D row = (lane>>4)*4+reg = h (verified layout), so s0,u0,u1,u2
// for one (point,h) all live in the same lane across the 4 type-accumulators.
// A/B k-mapping uses one shared convention for both operands -> any k-grouping
// mismatch with HW is a contraction-index permutation and cancels exactly.
__global__ __launch_bounds__(BLK, 2) void curl_mfma(
    const float* __restrict__ x,  const float* __restrict__ W1,
    const float* __restrict__ b1, const float* __restrict__ W2,
    const float* __restrict__ b2, const float* __restrict__ W3,
    float* __restrict__ out, int npts, int iters, int ntiles)
{
    __shared__ ushort sX[NWAVE][2][64][KPAD];   // [wave][hi/lo][col=type*16+p][k] 72.0 KiB
    __shared__ float4 sLUT[64];                 // {b2[h], W3[0][h], W3[1][h], W3[2][h]}

    const int tid  = threadIdx.x;
    const int wv   = tid >> 6;
    const int lane = tid & 63;
    const int p    = lane & 15;   // point-in-tile == B col == D col
    const int q    = lane >> 4;   // k-group for A/B, h-subgroup for D

    if (tid < 64)
        sLUT[tid] = make_float4(b2[tid], W3[tid], W3[64 + tid], W3[128 + tid]);

    // A fragments: W2 rows m*16+p, k = kc*32 + q*8 + [0..7]; hi/lo split. Built once.
    bf16x8 Ahi[4][2], Alo[4][2];
#pragma unroll
    for (int m = 0; m < 4; ++m)
#pragma unroll
        for (int kc = 0; kc < 2; ++kc) {
            const float* src = W2 + (m * 16 + p) * 64 + kc * 32 + q * 8;
            const float4 va = ((const float4*)src)[0];
            const float4 vb = ((const float4*)src)[1];
            const float vv[8] = {va.x, va.y, va.z, va.w, vb.x, vb.y, vb.z, vb.w};
            unsigned int hb[8], lb[8];
#pragma unroll
            for (int j = 0; j < 8; ++j) {
                const unsigned int bits = __float_as_uint(vv[j]);
                const unsigned int h = bits & 0xffff0000u;
                hb[j] = h;
                lb[j] = __float_as_uint(vv[j] - __uint_as_float(h));
            }
            U4 uh, ul;
            uh.u = make_uint4(packlohi(hb[0],hb[1]), packlohi(hb[2],hb[3]),
                              packlohi(hb[4],hb[5]), packlohi(hb[6],hb[7]));
            ul.u = make_uint4(packlohi(lb[0],lb[1]), packlohi(lb[2],lb[3]),
                              packlohi(lb[4],lb[5]), packlohi(lb[6],lb[7]));
            Ahi[m][kc] = uh.v;
            Alo[m][kc] = ul.v;
        }
    __syncthreads();

    const int gw = blockIdx.x * NWAVE + wv;
    const int nw = gridDim.x * NWAVE;

    for (int it = 0; it < iters; ++it) {          // uniform trip count: barrier-safe
        const int tile = gw + it * nw;
        const bool act = tile < ntiles;
        const int id = tile * NPT + p;

        float x0 = 0.f, x1 = 0.f, x2 = 0.f;
        if (act && id < npts) {
            x0 = x[id * 3 + 0];
            x1 = x[id * 3 + 1];
            x2 = x[id * 3 + 2];
        }

        // ---- Layer 1 + g = D1*W1col for this lane's 16 k's; split + LDS write ----
        if (act) {
#pragma unroll
            for (int half = 0; half < 2; ++half) {
                const int k0 = q * 16 + half * 8;
                float fw[24], fb[8];
                {
                    const float4* wp = (const float4*)(W1 + k0 * 3);
#pragma unroll
                    for (int z = 0; z < 6; ++z) {
                        const float4 t4 = wp[z];
                        fw[4*z] = t4.x; fw[4*z+1] = t4.y; fw[4*z+2] = t4.z; fw[4*z+3] = t4.w;
                    }
                    const float4* bp = (const float4*)(b1 + k0);
                    float4 t4 = bp[0];
                    fb[0] = t4.x; fb[1] = t4.y; fb[2] = t4.z; fb[3] = t4.w;
                    t4 = bp[1];
                    fb[4] = t4.x; fb[5] = t4.y; fb[6] = t4.z; fb[7] = t4.w;
                }
                float vh[8], v0[8], v1[8], v2[8];
#pragma unroll
                for (int j = 0; j < 8; ++j) {
                    const float w10 = fw[3*j], w11 = fw[3*j+1], w12 = fw[3*j+2];
                    float a = fmaf(w10, x0, fb[j]);
                    a = fmaf(w11, x1, a);
                    a = fmaf(w12, x2, a);
                    const float th = tanh_fast(a);
                    const float d1 = fmaf(-th, th, 1.0f);
                    vh[j] = th;
                    v0[j] = d1 * w10;
                    v1[j] = d1 * w11;
                    v2[j] = d1 * w12;
                }
                store8(&sX[wv][0][0*16 + p][k0], &sX[wv][1][0*16 + p][k0], vh);
                store8(&sX[wv][0][1*16 + p][k0], &sX[wv][1][1*16 + p][k0], v0);
                store8(&sX[wv][0][2*16 + p][k0], &sX[wv][1][2*16 + p][k0], v1);
                store8(&sX[wv][0][3*16 + p][k0], &sX[wv][1][3*16 + p][k0], v2);
            }
        }
        __syncthreads();

        // ---- MFMA: 4 types x 4 M-tiles x 2 k-chunks x 3 split-terms ----
        float c0 = 0.f, c1 = 0.f, c2 = 0.f;
        if (act) {
            bf16x8 Bhi[4][2], Blo[4][2];
#pragma unroll
            for (int t = 0; t < 4; ++t)
#pragma unroll
                for (int kc = 0; kc < 2; ++kc) {
                    const int koff = kc * 32 + q * 8;
                    Bhi[t][kc] = *(const bf16x8*)&sX[wv][0][t*16 + p][koff];
                    Blo[t][kc] = *(const bf16x8*)&sX[wv][1][t*16 + p][koff];
                }
#pragma unroll
            for (int m = 0; m < 4; ++m) {
                f32x4 a0 = {0.f,0.f,0.f,0.f}, a1 = a0, a2 = a0, a3 = a0;
#pragma unroll
                for (int kc = 0; kc < 2; ++kc) {
                    a0 = MFMA(Ahi[m][kc], Bhi[0][kc], a0, 0, 0, 0);
                    a1 = MFMA(Ahi[m][kc], Bhi[1][kc], a1, 0, 0, 0);
                    a2 = MFMA(Ahi[m][kc], Bhi[2][kc], a2, 0, 0, 0);
                    a3 = MFMA(Ahi[m][kc], Bhi[3][kc], a3, 0, 0, 0);
                    a0 = MFMA(Ahi[m][kc], Blo[0][kc], a0, 0, 0, 0);
                    a1 = MFMA(Ahi[m][kc], Blo[1][kc], a1, 0, 0, 0);
                    a2 = MFMA(Ahi[m][kc], Blo[2][kc], a2, 0, 0, 0);
                    a3 = MFMA(Ahi[m][kc], Blo[3][kc], a3, 0, 0, 0);
                    a0 = MFMA(Alo[m][kc], Bhi[0][kc], a0, 0, 0, 0);
                    a1 = MFMA(Alo[m][kc], Bhi[1][kc], a1, 0, 0, 0);
                    a2 = MFMA(Alo[m][kc], Bhi[2][kc], a2, 0, 0, 0);
                    a3 = MFMA(Alo[m][kc], Bhi[3][kc], a3, 0, 0, 0);
                }
                // Epilogue for h = m*16 + q*4 + r (lane-local: a0=s0pre, a1=u0, a2=u1, a3=u2)
#pragma unroll
                for (int r = 0; r < 4; ++r) {
                    const float4 lut = sLUT[m*16 + q*4 + r];
                    const float s0 = a0[r] + lut.x;
                    const float th = tanh_fast(s0);
                    const float d2 = fmaf(-th, th, 1.0f);
                    const float e0 = lut.y * d2, e1 = lut.z * d2, e2 = lut.w * d2;
                    c0 = fmaf(e2, a2[r], c0); c0 = fmaf(-e1, a3[r], c0);
                    c1 = fmaf(e0, a3[r], c1); c1 = fmaf(-e2, a1[r], c1);
                    c2 = fmaf(e1, a1[r], c2); c2 = fmaf(-e0, a2[r], c2);
                }
            }
        }
        __syncthreads();   // reads of sX done before next iteration overwrites

        // Reduce partial curls over the 4 h-subgroups (lanes 16 apart), then store.
        c0 += __shfl_xor(c0, 16); c0 += __shfl_xor(c0, 32);
        c1 += __shfl_xor(c1, 16); c1 += __shfl_xor(c1, 32);
        c2 += __shfl_xor(c2, 16); c2 += __shfl_xor(c2, 32);
        if (act && q == 0 && id < npts) {
            out[id * 3 + 0] = c0;
            out[id * 3 + 1] = c1;
            out[id * 3 + 2] = c2;
        }
    }
}

extern "C" void kernel_launch(void* const* d_in, const int* in_sizes, int n_in,
                              void* d_out, int out_size, void* d_ws, size_t ws_size,
                              hipStream_t stream) {
    const float* x  = (const float*)d_in[0];
    const float* W1 = (const float*)d_in[1];
    const float* b1 = (const float*)d_in[2];
    const float* W2 = (const float*)d_in[3];
    const float* b2 = (const float*)d_in[4];
    const float* W3 = (const float*)d_in[5];
    // d_in[6] (b3) unused: it cancels in the Jacobian.
    float* out = (float*)d_out;

    const int npts   = in_sizes[0] / 3;
    const int ntiles = (npts + NPT - 1) / NPT;
    int blocks = (ntiles + NWAVE - 1) / NWAVE;
    if (blocks > MAXB) blocks = MAXB;
    const int nw    = blocks * NWAVE;
    const int iters = (ntiles + nw - 1) / nw;

    hipLaunchKernelGGL(curl_mfma, dim3(blocks), dim3(BLK), 0, stream,
                       x, W1, b1, W2, b2, W3, out, npts, iters, ntiles);
}

// Round 4
// 146.492 us; speedup vs baseline: 2.7757x; 1.0472x over previous
//
#include <hip/hip_runtime.h>

typedef __attribute__((ext_vector_type(8))) short bf16x8;   // 8 bf16 in 4 VGPRs
typedef __attribute__((ext_vector_type(4))) float f32x4;

#define BLK   256
#define NWAVE 4
#define NPT   16      // points per wave-tile
#define MAXB  512     // exactly 2 blocks/CU resident -> perfectly balanced

union U4 { uint4 u; bf16x8 v; };

// tanh(x) = 1 - 2/(exp(2x)+1); ~1 ulp, saturates correctly.
__device__ __forceinline__ float tanh_fast(float v) {
    float e = __builtin_amdgcn_exp2f(v * 2.8853900817779268f);
    float r = __builtin_amdgcn_rcpf(e + 1.0f);
    return fmaf(-2.0f, r, 1.0f);
}

__device__ __forceinline__ unsigned int packlohi(unsigned int a, unsigned int b) {
    // a,b are fp32 bit patterns; result bf16x2 = {bf16(a) low, bf16(b) high} (truncation)
    return (a >> 16) | (b & 0xffff0000u);
}

// Split 8 fp32 into bf16 hi (truncate) + lo (residual) register fragments.
__device__ __forceinline__ void pack8(const float* v, bf16x8* hi, bf16x8* lo) {
    unsigned int hb[8], lb[8];
#pragma unroll
    for (int j = 0; j < 8; ++j) {
        const unsigned int bits = __float_as_uint(v[j]);
        const unsigned int h = bits & 0xffff0000u;
        hb[j] = h;
        lb[j] = __float_as_uint(v[j] - __uint_as_float(h));
    }
    U4 uh, ul;
    uh.u = make_uint4(packlohi(hb[0],hb[1]), packlohi(hb[2],hb[3]),
                      packlohi(hb[4],hb[5]), packlohi(hb[6],hb[7]));
    ul.u = make_uint4(packlohi(lb[0],lb[1]), packlohi(lb[2],lb[3]),
                      packlohi(lb[4],lb[5]), packlohi(lb[6],lb[7]));
    *hi = uh.v;
    *lo = ul.v;
}

#define MFMA __builtin_amdgcn_mfma_f32_16x16x32_bf16

// Barrier-free GEMM-ified curl. Shared k-permutation kappa(q,kc,j)=q*16+kc*8+j for
// BOTH MFMA operands (it cancels in the contraction) is chosen so the B fragment
// in lane (p,q) is exactly what that lane computes in layer 1 for its own point p:
// NO LDS staging of X, no per-tile __syncthreads, waves fully independent.
// C/D layout (HW-verified): col=lane&15=p, row=(lane>>4)*4+reg -> h=m*16+q*4+r,
// so s0/u0/u1/u2 for one (point,h) are lane-local across the 4 accumulators.
__global__ __launch_bounds__(BLK, 2) void curl_mfma(
    const float* __restrict__ x,  const float* __restrict__ W1,
    const float* __restrict__ b1, const float* __restrict__ W2,
    const float* __restrict__ b2, const float* __restrict__ W3,
    float* __restrict__ out, int npts, int iters, int ntiles)
{
    __shared__ float4 sLUT[64];   // {b2[h], W3[0][h], W3[1][h], W3[2][h]} — 1 KiB

    const int tid  = threadIdx.x;
    const int wv   = tid >> 6;
    const int lane = tid & 63;
    const int p    = lane & 15;   // point-in-tile == B col == D col
    const int q    = lane >> 4;   // k-group (kappa) and h-subgroup of D

    if (tid < 64)
        sLUT[tid] = make_float4(b2[tid], W3[tid], W3[64 + tid], W3[128 + tid]);

    // A fragments (once per wave): W2 row m*16+p, k = kappa(q,kc,j) = q*16+kc*8+j.
    bf16x8 Ahi[4][2], Alo[4][2];
#pragma unroll
    for (int m = 0; m < 4; ++m)
#pragma unroll
        for (int kc = 0; kc < 2; ++kc) {
            const float* src = W2 + (m * 16 + p) * 64 + q * 16 + kc * 8;
            const float4 va = ((const float4*)src)[0];
            const float4 vb = ((const float4*)src)[1];
            const float vv[8] = {va.x, va.y, va.z, va.w, vb.x, vb.y, vb.z, vb.w};
            pack8(vv, &Ahi[m][kc], &Alo[m][kc]);
        }

    // Layer-1 weights for this lane's 16 k's (k = q*16 + 0..15): loop-invariant.
    float fw[48], fb[16];
    {
        const float4* wp = (const float4*)(W1 + q * 16 * 3);   // 48 consecutive floats
#pragma unroll
        for (int z = 0; z < 12; ++z) {
            const float4 t4 = wp[z];
            fw[4*z] = t4.x; fw[4*z+1] = t4.y; fw[4*z+2] = t4.z; fw[4*z+3] = t4.w;
        }
        const float4* bp = (const float4*)(b1 + q * 16);
#pragma unroll
        for (int z = 0; z < 4; ++z) {
            const float4 t4 = bp[z];
            fb[4*z] = t4.x; fb[4*z+1] = t4.y; fb[4*z+2] = t4.z; fb[4*z+3] = t4.w;
        }
    }
    __syncthreads();   // sLUT ready; no barriers after this point

    const int gw = blockIdx.x * NWAVE + wv;
    const int nw = gridDim.x * NWAVE;

    for (int it = 0; it < iters; ++it) {
        const int tile = gw + it * nw;
        if (tile >= ntiles) break;         // no barriers -> divergent exit is safe
        const int id = tile * NPT + p;

        float x0 = 0.f, x1 = 0.f, x2 = 0.f;
        if (id < npts) {
            x0 = x[id * 3 + 0];
            x1 = x[id * 3 + 1];
            x2 = x[id * 3 + 2];
        }

        // ---- Layer 1 + g = D1*W1col; pack straight into B register fragments ----
        bf16x8 Bhi[4][2], Blo[4][2];       // [type][kc]
#pragma unroll
        for (int kc = 0; kc < 2; ++kc) {
            float vh[8], v0[8], v1[8], v2[8];
#pragma unroll
            for (int j = 0; j < 8; ++j) {
                const int jj = kc * 8 + j;
                const float w10 = fw[3*jj], w11 = fw[3*jj+1], w12 = fw[3*jj+2];
                float a = fmaf(w10, x0, fb[jj]);
                a = fmaf(w11, x1, a);
                a = fmaf(w12, x2, a);
                const float th = tanh_fast(a);
                const float d1 = fmaf(-th, th, 1.0f);
                vh[j] = th;
                v0[j] = d1 * w10;
                v1[j] = d1 * w11;
                v2[j] = d1 * w12;
            }
            pack8(vh, &Bhi[0][kc], &Blo[0][kc]);
            pack8(v0, &Bhi[1][kc], &Blo[1][kc]);
            pack8(v1, &Bhi[2][kc], &Blo[2][kc]);
            pack8(v2, &Bhi[3][kc], &Blo[3][kc]);
        }

        // ---- MFMA: 4 M-tiles x 2 k-chunks x 3 split-terms x 4 types = 96 ----
        float c0 = 0.f, c1 = 0.f, c2 = 0.f;
#pragma unroll
        for (int m = 0; m < 4; ++m) {
            f32x4 a0 = {0.f,0.f,0.f,0.f}, a1 = a0, a2 = a0, a3 = a0;
#pragma unroll
            for (int kc = 0; kc < 2; ++kc) {
                a0 = MFMA(Ahi[m][kc], Bhi[0][kc], a0, 0, 0, 0);
                a1 = MFMA(Ahi[m][kc], Bhi[1][kc], a1, 0, 0, 0);
                a2 = MFMA(Ahi[m][kc], Bhi[2][kc], a2, 0, 0, 0);
                a3 = MFMA(Ahi[m][kc], Bhi[3][kc], a3, 0, 0, 0);
                a0 = MFMA(Ahi[m][kc], Blo[0][kc], a0, 0, 0, 0);
                a1 = MFMA(Ahi[m][kc], Blo[1][kc], a1, 0, 0, 0);
                a2 = MFMA(Ahi[m][kc], Blo[2][kc], a2, 0, 0, 0);
                a3 = MFMA(Ahi[m][kc], Blo[3][kc], a3, 0, 0, 0);
                a0 = MFMA(Alo[m][kc], Bhi[0][kc], a0, 0, 0, 0);
                a1 = MFMA(Alo[m][kc], Bhi[1][kc], a1, 0, 0, 0);
                a2 = MFMA(Alo[m][kc], Bhi[2][kc], a2, 0, 0, 0);
                a3 = MFMA(Alo[m][kc], Bhi[3][kc], a3, 0, 0, 0);
            }
            // Epilogue for h = m*16 + q*4 + r (a0=s0pre, a1=u0, a2=u1, a3=u2)
#pragma unroll
            for (int r = 0; r < 4; ++r) {
                const float4 lut = sLUT[m*16 + q*4 + r];
                const float s0 = a0[r] + lut.x;
                const float th = tanh_fast(s0);
                const float d2 = fmaf(-th, th, 1.0f);
                const float e0 = lut.y * d2, e1 = lut.z * d2, e2 = lut.w * d2;
                c0 = fmaf(e2, a2[r], c0); c0 = fmaf(-e1, a3[r], c0);
                c1 = fmaf(e0, a3[r], c1); c1 = fmaf(-e2, a1[r], c1);
                c2 = fmaf(e1, a1[r], c2); c2 = fmaf(-e0, a2[r], c2);
            }
        }

        // Reduce partial curls over the 4 h-subgroups (q dimension).
        c0 += __shfl_xor(c0, 16); c0 += __shfl_xor(c0, 32);
        c1 += __shfl_xor(c1, 16); c1 += __shfl_xor(c1, 32);
        c2 += __shfl_xor(c2, 16); c2 += __shfl_xor(c2, 32);

        // Coalesced store: lane (p,q<3) writes component q of point p ->
        // 48 contiguous dwords per tile.
        if (q < 3 && id < npts) {
            const float cv = (q == 0) ? c0 : ((q == 1) ? c1 : c2);
            out[tile * (NPT * 3) + p * 3 + q] = cv;
        }
    }
}

extern "C" void kernel_launch(void* const* d_in, const int* in_sizes, int n_in,
                              void* d_out, int out_size, void* d_ws, size_t ws_size,
                              hipStream_t stream) {
    const float* x  = (const float*)d_in[0];
    const float* W1 = (const float*)d_in[1];
    const float* b1 = (const float*)d_in[2];
    const float* W2 = (const float*)d_in[3];
    const float* b2 = (const float*)d_in[4];
    const float* W3 = (const float*)d_in[5];
    // d_in[6] (b3) unused: it cancels in the Jacobian.
    float* out = (float*)d_out;

    const int npts   = in_sizes[0] / 3;
    const int ntiles = (npts + NPT - 1) / NPT;
    int blocks = (ntiles + NWAVE - 1) / NWAVE;
    if (blocks > MAXB) blocks = MAXB;
    const int nw    = blocks * NWAVE;
    const int iters = (ntiles + nw - 1) / nw;

    hipLaunchKernelGGL(curl_mfma, dim3(blocks), dim3(BLK), 0, stream,
                       x, W1, b1, W2, b2, W3, out, npts, iters, ntiles);
}

// Round 5
// 130.407 us; speedup vs baseline: 3.1180x; 1.1233x over previous
//
#include <hip/hip_runtime.h>

typedef __attribute__((ext_vector_type(8))) short bf16x8;   // 8 bf16 in 4 VGPRs
typedef __attribute__((ext_vector_type(4))) float f32x4;

#define BLK   256
#define NWAVE 4
#define NPT   16      // points per wave-tile
#define MAXB  1024    // 4 blocks/CU -> 16 waves/CU = 4 waves/SIMD (VGPR=128 allows it)

union U4 { uint4 u; bf16x8 v; };

// tanh(x) = 1 - 2/(exp(2x)+1); ~1 ulp, saturates correctly.
__device__ __forceinline__ float tanh_fast(float v) {
    float e = __builtin_amdgcn_exp2f(v * 2.8853900817779268f);
    float r = __builtin_amdgcn_rcpf(e + 1.0f);
    return fmaf(-2.0f, r, 1.0f);
}

// {bf16(a) in low16, bf16(b) in high16} (truncation) = one v_perm_b32:
// result bytes {a.b2, a.b3, b.b2, b.b3}; {S0,S1} byte pool: S1=bytes0-3, S0=bytes4-7.
__device__ __forceinline__ unsigned int packlohi(unsigned int a, unsigned int b) {
    return __builtin_amdgcn_perm(b, a, 0x07060302u);
}

// Split 8 fp32 into bf16 hi (truncate) + lo (residual) register fragments.
__device__ __forceinline__ void pack8(const float* v, bf16x8* hi, bf16x8* lo) {
    unsigned int hb[8], lb[8];
#pragma unroll
    for (int j = 0; j < 8; ++j) {
        const unsigned int bits = __float_as_uint(v[j]);
        const unsigned int h = bits & 0xffff0000u;
        hb[j] = h;
        lb[j] = __float_as_uint(v[j] - __uint_as_float(h));
    }
    U4 uh, ul;
    uh.u = make_uint4(packlohi(hb[0],hb[1]), packlohi(hb[2],hb[3]),
                      packlohi(hb[4],hb[5]), packlohi(hb[6],hb[7]));
    ul.u = make_uint4(packlohi(lb[0],lb[1]), packlohi(lb[2],lb[3]),
                      packlohi(lb[4],lb[5]), packlohi(lb[6],lb[7]));
    *hi = uh.v;
    *lo = ul.v;
}

#define MFMA __builtin_amdgcn_mfma_f32_16x16x32_bf16

// Barrier-free GEMM-ified curl. Shared k-permutation kappa(q,kc,j)=q*16+kc*8+j for
// BOTH MFMA operands (it cancels in the contraction) is chosen so the B fragment
// in lane (p,q) is exactly what that lane computes in layer 1 for its own point p:
// NO LDS staging of X, no per-tile __syncthreads, waves fully independent.
// C/D layout (HW-verified): col=lane&15=p, row=(lane>>4)*4+reg -> h=m*16+q*4+r,
// so s0/u0/u1/u2 for one (point,h) are lane-local across the 4 accumulators.
__global__ __launch_bounds__(BLK, 2) void curl_mfma(
    const float* __restrict__ x,  const float* __restrict__ W1,
    const float* __restrict__ b1, const float* __restrict__ W2,
    const float* __restrict__ b2, const float* __restrict__ W3,
    float* __restrict__ out, int npts, int iters, int ntiles)
{
    __shared__ float4 sLUT[64];   // {b2[h], W3[0][h], W3[1][h], W3[2][h]} — 1 KiB

    const int tid  = threadIdx.x;
    const int wv   = tid >> 6;
    const int lane = tid & 63;
    const int p    = lane & 15;   // point-in-tile == B col == D col
    const int q    = lane >> 4;   // k-group (kappa) and h-subgroup of D

    if (tid < 64)
        sLUT[tid] = make_float4(b2[tid], W3[tid], W3[64 + tid], W3[128 + tid]);

    // A fragments (once per wave): W2 row m*16+p, k = kappa(q,kc,j) = q*16+kc*8+j.
    bf16x8 Ahi[4][2], Alo[4][2];
#pragma unroll
    for (int m = 0; m < 4; ++m)
#pragma unroll
        for (int kc = 0; kc < 2; ++kc) {
            const float* src = W2 + (m * 16 + p) * 64 + q * 16 + kc * 8;
            const float4 va = ((const float4*)src)[0];
            const float4 vb = ((const float4*)src)[1];
            const float vv[8] = {va.x, va.y, va.z, va.w, vb.x, vb.y, vb.z, vb.w};
            pack8(vv, &Ahi[m][kc], &Alo[m][kc]);
        }

    // Layer-1 weights for this lane's 16 k's (k = q*16 + 0..15): loop-invariant.
    float fw[48], fb[16];
    {
        const float4* wp = (const float4*)(W1 + q * 16 * 3);   // 48 consecutive floats
#pragma unroll
        for (int z = 0; z < 12; ++z) {
            const float4 t4 = wp[z];
            fw[4*z] = t4.x; fw[4*z+1] = t4.y; fw[4*z+2] = t4.z; fw[4*z+3] = t4.w;
        }
        const float4* bp = (const float4*)(b1 + q * 16);
#pragma unroll
        for (int z = 0; z < 4; ++z) {
            const float4 t4 = bp[z];
            fb[4*z] = t4.x; fb[4*z+1] = t4.y; fb[4*z+2] = t4.z; fb[4*z+3] = t4.w;
        }
    }
    __syncthreads();   // sLUT ready; no barriers after this point

    const int gw = blockIdx.x * NWAVE + wv;
    const int nw = gridDim.x * NWAVE;

    for (int it = 0; it < iters; ++it) {
        const int tile = gw + it * nw;
        if (tile >= ntiles) break;         // no barriers -> divergent exit is safe
        const int id = tile * NPT + p;

        float x0 = 0.f, x1 = 0.f, x2 = 0.f;
        if (id < npts) {
            x0 = x[id * 3 + 0];
            x1 = x[id * 3 + 1];
            x2 = x[id * 3 + 2];
        }

        // ---- Layer 1 + g = D1*W1col; pack straight into B register fragments ----
        bf16x8 Bhi[4][2], Blo[4][2];       // [type][kc]
#pragma unroll
        for (int kc = 0; kc < 2; ++kc) {
            float vh[8], v0[8], v1[8], v2[8];
#pragma unroll
            for (int j = 0; j < 8; ++j) {
                const int jj = kc * 8 + j;
                const float w10 = fw[3*jj], w11 = fw[3*jj+1], w12 = fw[3*jj+2];
                float a = fmaf(w10, x0, fb[jj]);
                a = fmaf(w11, x1, a);
                a = fmaf(w12, x2, a);
                const float th = tanh_fast(a);
                const float d1 = fmaf(-th, th, 1.0f);
                vh[j] = th;
                v0[j] = d1 * w10;
                v1[j] = d1 * w11;
                v2[j] = d1 * w12;
            }
            pack8(vh, &Bhi[0][kc], &Blo[0][kc]);
            pack8(v0, &Bhi[1][kc], &Blo[1][kc]);
            pack8(v1, &Bhi[2][kc], &Blo[2][kc]);
            pack8(v2, &Bhi[3][kc], &Blo[3][kc]);
        }

        // ---- MFMA: 4 M-tiles x 2 k-chunks x 3 split-terms x 4 types = 96 ----
        float c0 = 0.f, c1 = 0.f, c2 = 0.f;
#pragma unroll
        for (int m = 0; m < 4; ++m) {
            f32x4 a0 = {0.f,0.f,0.f,0.f}, a1 = a0, a2 = a0, a3 = a0;
#pragma unroll
            for (int kc = 0; kc < 2; ++kc) {
                a0 = MFMA(Ahi[m][kc], Bhi[0][kc], a0, 0, 0, 0);
                a1 = MFMA(Ahi[m][kc], Bhi[1][kc], a1, 0, 0, 0);
                a2 = MFMA(Ahi[m][kc], Bhi[2][kc], a2, 0, 0, 0);
                a3 = MFMA(Ahi[m][kc], Bhi[3][kc], a3, 0, 0, 0);
                a0 = MFMA(Ahi[m][kc], Blo[0][kc], a0, 0, 0, 0);
                a1 = MFMA(Ahi[m][kc], Blo[1][kc], a1, 0, 0, 0);
                a2 = MFMA(Ahi[m][kc], Blo[2][kc], a2, 0, 0, 0);
                a3 = MFMA(Ahi[m][kc], Blo[3][kc], a3, 0, 0, 0);
                a0 = MFMA(Alo[m][kc], Bhi[0][kc], a0, 0, 0, 0);
                a1 = MFMA(Alo[m][kc], Bhi[1][kc], a1, 0, 0, 0);
                a2 = MFMA(Alo[m][kc], Bhi[2][kc], a2, 0, 0, 0);
                a3 = MFMA(Alo[m][kc], Bhi[3][kc], a3, 0, 0, 0);
            }
            // Epilogue for h = m*16 + q*4 + r (a0=s0pre, a1=u0, a2=u1, a3=u2)
#pragma unroll
            for (int r = 0; r < 4; ++r) {
                const float4 lut = sLUT[m*16 + q*4 + r];
                const float s0 = a0[r] + lut.x;
                const float th = tanh_fast(s0);
                const float d2 = fmaf(-th, th, 1.0f);
                const float e0 = lut.y * d2, e1 = lut.z * d2, e2 = lut.w * d2;
                c0 = fmaf(e2, a2[r], c0); c0 = fmaf(-e1, a3[r], c0);
                c1 = fmaf(e0, a3[r], c1); c1 = fmaf(-e2, a1[r], c1);
                c2 = fmaf(e1, a1[r], c2); c2 = fmaf(-e0, a2[r], c2);
            }
        }

        // Reduce partial curls over the 4 h-subgroups (q dimension).
        c0 += __shfl_xor(c0, 16); c0 += __shfl_xor(c0, 32);
        c1 += __shfl_xor(c1, 16); c1 += __shfl_xor(c1, 32);
        c2 += __shfl_xor(c2, 16); c2 += __shfl_xor(c2, 32);

        // Coalesced store: lane (p,q<3) writes component q of point p ->
        // 48 contiguous dwords per tile.
        if (q < 3 && id < npts) {
            const float cv = (q == 0) ? c0 : ((q == 1) ? c1 : c2);
            out[tile * (NPT * 3) + p * 3 + q] = cv;
        }
    }
}

extern "C" void kernel_launch(void* const* d_in, const int* in_sizes, int n_in,
                              void* d_out, int out_size, void* d_ws, size_t ws_size,
                              hipStream_t stream) {
    const float* x  = (const float*)d_in[0];
    const float* W1 = (const float*)d_in[1];
    const float* b1 = (const float*)d_in[2];
    const float* W2 = (const float*)d_in[3];
    const float* b2 = (const float*)d_in[4];
    const float* W3 = (const float*)d_in[5];
    // d_in[6] (b3) unused: it cancels in the Jacobian.
    float* out = (float*)d_out;

    const int npts   = in_sizes[0] / 3;
    const int ntiles = (npts + NPT - 1) / NPT;
    int blocks = (ntiles + NWAVE - 1) / NWAVE;
    if (blocks > MAXB) blocks = MAXB;
    const int nw    = blocks * NWAVE;
    const int iters = (ntiles + nw - 1) / nw;

    hipLaunchKernelGGL(curl_mfma, dim3(blocks), dim3(BLK), 0, stream,
                       x, W1, b1, W2, b2, W3, out, npts, iters, ntiles);
}